// Round 1
// baseline (117.127 us; speedup 1.0000x reference)
//
#include <hip/hip_runtime.h>
#include <math.h>

// ParagraphVector fused forward:
//   review_emb = review_emb_table[review_ids]                     [B,128]
//   pos[b,w]   = dot(review_word_emb[b,w,:], review_emb[b,:])
//   neg[b,w,j] = dot(word_emb_table[neg_idxs[b, w*NN+j]], review_emb[b,:])
//   loss[b]    = sum_w mask * (softplus(-pos) + sum_j softplus(neg)) / max(sum mask,1)
//
// One 64-lane wave per review; lane holds float2 of the 128-dim embedding.

__device__ __forceinline__ float stable_softplus(float x) {
    // softplus(x) = max(x,0) + log1p(exp(-|x|))  -- overflow-safe
    return fmaxf(x, 0.0f) + log1pf(__expf(-fabsf(x)));
}

__device__ __forceinline__ float wave_reduce_sum(float v) {
    // 64-lane butterfly (wavefront = 64 on CDNA!)
    v += __shfl_xor(v, 32);
    v += __shfl_xor(v, 16);
    v += __shfl_xor(v, 8);
    v += __shfl_xor(v, 4);
    v += __shfl_xor(v, 2);
    v += __shfl_xor(v, 1);
    return v;
}

__global__ void __launch_bounds__(256)
pv_fused_kernel(const int* __restrict__ review_ids,      // [B]
                const float* __restrict__ rw_emb,        // [B, W, 128]
                const float* __restrict__ mask,          // [B, W]
                const int* __restrict__ neg_idxs,        // [B, W*NN]
                const float* __restrict__ word_tab,      // [VOCAB, 128]
                const float* __restrict__ rev_tab,       // [RC, 128]
                float* __restrict__ out_rev,             // [B, 128]
                float* __restrict__ out_loss,            // [B]
                int B, int W, int NN)
{
    const int wave = threadIdx.x >> 6;
    const int lane = threadIdx.x & 63;
    const int waves_per_blk = blockDim.x >> 6;
    const int b = blockIdx.x * waves_per_blk + wave;
    if (b >= B) return;

    const int E = 128;   // float2 per lane * 64 lanes

    const int rid = review_ids[b];
    const float2 r = *reinterpret_cast<const float2*>(
        rev_tab + (size_t)rid * E + lane * 2);

    // output 0: the gathered review embedding (exact copy)
    *reinterpret_cast<float2*>(out_rev + (size_t)b * E + lane * 2) = r;

    float loss_acc = 0.0f;
    float cnt = 0.0f;

    const int WN = W * NN;
    for (int w = 0; w < W; ++w) {
        const float m = mask[(size_t)b * W + w];   // uniform address -> broadcast
        cnt += m;

        const float2 x = *reinterpret_cast<const float2*>(
            rw_emb + ((size_t)b * W + w) * E + lane * 2);
        const float pos = wave_reduce_sum(fmaf(x.x, r.x, x.y * r.y));
        float lw = stable_softplus(-pos);

        #pragma unroll
        for (int j = 0; j < 5; ++j) {
            if (j >= NN) break;
            const int ni = neg_idxs[(size_t)b * WN + w * NN + j];
            const float2 nv = *reinterpret_cast<const float2*>(
                word_tab + (size_t)ni * E + lane * 2);
            const float ns = wave_reduce_sum(fmaf(nv.x, r.x, nv.y * r.y));
            lw += stable_softplus(ns);
        }
        loss_acc += lw * m;
    }

    if (lane == 0) {
        out_loss[b] = loss_acc / fmaxf(cnt, 1.0f);
    }
}

extern "C" void kernel_launch(void* const* d_in, const int* in_sizes, int n_in,
                              void* d_out, int out_size, void* d_ws, size_t ws_size,
                              hipStream_t stream)
{
    const int*   review_ids = (const int*)  d_in[0];
    const float* rw_emb     = (const float*)d_in[1];
    const float* mask       = (const float*)d_in[2];
    const int*   neg_idxs   = (const int*)  d_in[3];
    const float* word_tab   = (const float*)d_in[4];
    const float* rev_tab    = (const float*)d_in[5];
    // d_in[6] = n_negs scalar; derivable from sizes instead.

    const int B  = in_sizes[0];
    const int BW = in_sizes[2];          // B*W
    const int W  = BW / B;
    const int NN = in_sizes[3] / BW;     // n_negs

    float* out_rev  = (float*)d_out;
    float* out_loss = (float*)d_out + (size_t)B * 128;

    const int waves_per_blk = 4;                 // 256 threads
    const int grid = (B + waves_per_blk - 1) / waves_per_blk;
    pv_fused_kernel<<<grid, 256, 0, stream>>>(
        review_ids, rw_emb, mask, neg_idxs, word_tab, rev_tab,
        out_rev, out_loss, B, W, NN);
}

// Round 2
// 52.193 us; speedup vs baseline: 2.2441x; 2.2441x over previous
//
#include <hip/hip_runtime.h>
#include <math.h>

// ParagraphVector fused forward, lane-per-dot layout:
//   review_emb = review_emb_table[review_ids]                     [B,128]
//   pos[b,w]   = dot(review_word_emb[b,w,:], review_emb[b,:])
//   neg[b,w,j] = dot(word_emb_table[neg_idxs[b,w*NN+j]], review_emb[b,:])
//   loss[b]    = sum_w mask*(sp(-pos) + sum_j sp(neg)) / max(sum mask,1)
//
// One 64-lane wave per review. r (128 f32) staged to a per-wave LDS slice;
// each lane owns ONE of the W + W*NN = 60 dot products (lanes 60..63 idle),
// reading r via uniform-address ds_read_b128 (broadcast) and its own row
// via float4. Only ONE final 6-step butterfly pair per review (loss + count)
// instead of 60 butterflies.

__device__ __forceinline__ float stable_softplus(float x) {
    // softplus(x) = max(x,0) + log1p(exp(-|x|))  -- overflow-safe
    return fmaxf(x, 0.0f) + log1pf(__expf(-fabsf(x)));
}

__global__ void __launch_bounds__(256)
pv_lanedot_kernel(const int* __restrict__ review_ids,      // [B]
                  const float* __restrict__ rw_emb,        // [B, W, 128]
                  const float* __restrict__ mask,          // [B, W]
                  const int* __restrict__ neg_idxs,        // [B, W*NN]
                  const float* __restrict__ word_tab,      // [VOCAB, 128]
                  const float* __restrict__ rev_tab,       // [RC, 128]
                  float* __restrict__ out_rev,             // [B, 128]
                  float* __restrict__ out_loss,            // [B]
                  int B, int W, int NN)
{
    __shared__ float lds_r[4][128];     // per-wave slice, no cross-wave sharing

    const int wave = threadIdx.x >> 6;
    const int lane = threadIdx.x & 63;
    const int b = blockIdx.x * (blockDim.x >> 6) + wave;
    if (b >= B) return;

    const int E = 128;

    // ---- gather review embedding, write output 0, stage to LDS ----
    const int rid = review_ids[b];
    const float2 r2 = *reinterpret_cast<const float2*>(
        rev_tab + (size_t)rid * E + lane * 2);
    *reinterpret_cast<float2*>(out_rev + (size_t)b * E + lane * 2) = r2;
    *reinterpret_cast<float2*>(&lds_r[wave][lane * 2]) = r2;
    // LDS slice is wave-private: same-wave write->read ordering is handled by
    // the compiler's lgkmcnt waits; no __syncthreads needed.

    // ---- lane -> dot assignment ----
    const int nd = W + W * NN;          // 60 for W=10,NN=5 (must be <= 64)
    const bool active = lane < nd;

    const float* row;
    float sgn;                          // softplus argument sign
    int w;                              // word this lane's term belongs to
    if (lane < W) {                     // positive sample, word = lane
        w = lane;
        row = rw_emb + ((size_t)b * W + lane) * E;
        sgn = -1.0f;
    } else if (active) {                // negative sample
        const int l = lane - W;         // 0 .. W*NN-1
        w = l / NN;
        const int ni = neg_idxs[(size_t)b * (W * NN) + l];
        row = word_tab + (size_t)ni * E;
        sgn = 1.0f;
    } else {                            // idle lane: harmless dummy row
        w = 0;
        row = word_tab;
        sgn = 1.0f;
    }
    const float m = active ? mask[(size_t)b * W + w] : 0.0f;

    // ---- per-lane serial dot: r broadcast from LDS, own row via float4 ----
    float acc = 0.0f;
    #pragma unroll
    for (int e = 0; e < 128; e += 4) {
        const float4 rv = *reinterpret_cast<const float4*>(&lds_r[wave][e]);
        const float4 xv = *reinterpret_cast<const float4*>(row + e);
        acc = fmaf(xv.x, rv.x, acc);
        acc = fmaf(xv.y, rv.y, acc);
        acc = fmaf(xv.z, rv.z, acc);
        acc = fmaf(xv.w, rv.w, acc);
    }

    float term = active ? m * stable_softplus(sgn * acc) : 0.0f;
    float cntv = (lane < W) ? m : 0.0f;

    // ---- single butterfly pair per review ----
    #pragma unroll
    for (int s = 32; s >= 1; s >>= 1) {
        term += __shfl_xor(term, s);
        cntv += __shfl_xor(cntv, s);
    }

    if (lane == 0) {
        out_loss[b] = term / fmaxf(cntv, 1.0f);
    }
}

extern "C" void kernel_launch(void* const* d_in, const int* in_sizes, int n_in,
                              void* d_out, int out_size, void* d_ws, size_t ws_size,
                              hipStream_t stream)
{
    const int*   review_ids = (const int*)  d_in[0];
    const float* rw_emb     = (const float*)d_in[1];
    const float* mask       = (const float*)d_in[2];
    const int*   neg_idxs   = (const int*)  d_in[3];
    const float* word_tab   = (const float*)d_in[4];
    const float* rev_tab    = (const float*)d_in[5];

    const int B  = in_sizes[0];
    const int BW = in_sizes[2];          // B*W
    const int W  = BW / B;
    const int NN = in_sizes[3] / BW;     // n_negs

    float* out_rev  = (float*)d_out;
    float* out_loss = (float*)d_out + (size_t)B * 128;

    const int waves_per_blk = 4;                 // 256 threads
    const int grid = (B + waves_per_blk - 1) / waves_per_blk;
    pv_lanedot_kernel<<<grid, 256, 0, stream>>>(
        review_ids, rw_emb, mask, neg_idxs, word_tab, rev_tab,
        out_rev, out_loss, B, W, NN);
}

// Round 4
// 42.321 us; speedup vs baseline: 2.7676x; 1.2333x over previous
//
#include <hip/hip_runtime.h>
#include <math.h>

// ParagraphVector fused forward, 16-lane-group-per-dot layout:
//   review_emb = review_emb_table[review_ids]                     [B,128]
//   pos[b,w]   = dot(review_word_emb[b,w,:], review_emb[b,:])
//   neg[b,w,j] = dot(word_emb_table[neg_idxs[b,w*NN+j]], review_emb[b,:])
//   loss[b]    = sum_w mask*(sp(-pos) + sum_j sp(neg)) / max(sum mask,1)
//
// One wave per review; each 16-lane quarter-wave owns one dot per pass
// (4 dots/pass, 15 passes for 60 dots). Lane reads float4 at sl*4 and
// 64+sl*4 -> every wave load instruction touches 16 distinct, fully-used
// cache lines. Dot reduce = 4-step __shfl_xor inside the group.
//
// CORRECTNESS NOTE (round-3 bug): all __shfl's live OUTSIDE divergent
// branches. ds_bpermute returns 0 for EXEC=0 source lanes, so a shfl
// inside the pos/neg branch silently corrupted ni on mixed passes.

__device__ __forceinline__ float stable_softplus(float x) {
    // softplus(x) = max(x,0) + log1p(exp(-|x|))  -- overflow-safe
    return fmaxf(x, 0.0f) + log1pf(__expf(-fabsf(x)));
}

__global__ void __launch_bounds__(256, 4)
pv_groupdot_kernel(const int* __restrict__ review_ids,      // [B]
                   const float* __restrict__ rw_emb,        // [B, W, 128]
                   const float* __restrict__ mask,          // [B, W]
                   const int* __restrict__ neg_idxs,        // [B, W*NN]
                   const float* __restrict__ word_tab,      // [VOCAB, 128]
                   const float* __restrict__ rev_tab,       // [RC, 128]
                   float* __restrict__ out_rev,             // [B, 128]
                   float* __restrict__ out_loss,            // [B]
                   int B, int W, int NN)
{
    const int wave = threadIdx.x >> 6;
    const int lane = threadIdx.x & 63;
    const int b = blockIdx.x * (blockDim.x >> 6) + wave;
    if (b >= B) return;

    const int E   = 128;
    const int sub = lane >> 4;     // quarter-wave (dot slot) 0..3
    const int sl  = lane & 15;     // lane within group

    const int WN = W * NN;         // 50
    const int nd = W + WN;         // 60 dots

    // ---- review embedding: 2 x float4 per lane (replicated across groups) ----
    const int rid = review_ids[b];
    const float4 rv1 = *reinterpret_cast<const float4*>(
        rev_tab + (size_t)rid * E + sl * 4);
    const float4 rv2 = *reinterpret_cast<const float4*>(
        rev_tab + (size_t)rid * E + 64 + sl * 4);

    // output 0: gathered review embedding (lanes 0..31 cover 128 dims)
    if (lane < 16) {
        *reinterpret_cast<float4*>(out_rev + (size_t)b * E + lane * 4) = rv1;
    } else if (lane < 32) {
        *reinterpret_cast<float4*>(out_rev + (size_t)b * E + lane * 4) = rv2;
    }

    // ---- coalesced prefetch of idxs and per-dot masks; broadcast via shfl ----
    const int idx_l = (lane < WN) ? neg_idxs[(size_t)b * WN + lane] : 0;
    // per-dot mask: dot 'lane' belongs to word w; one int-div total
    float md_l = 0.0f;
    if (lane < nd) {
        const int w = (lane < W) ? lane : (lane - W) / NN;
        md_l = mask[(size_t)b * W + w];
    }

    float loss_acc = 0.0f;

    const int npass = (nd + 3) >> 2;    // 15
    #pragma unroll 15
    for (int p = 0; p < npass; ++p) {
        const int d = p * 4 + sub;      // dot id, uniform within group

        // --- shfls first, NO divergence around them: every lane executes ---
        const bool is_pos = (d < W);
        const bool valid  = (d < nd);
        const int  ni     = __shfl(idx_l, valid ? (is_pos ? 0 : (d - W)) : 0);
        const float m_raw = __shfl(md_l, valid ? d : 0);
        const float m     = valid ? m_raw : 0.0f;

        // --- branchless row select ---
        const float* row = is_pos
            ? rw_emb + ((size_t)b * W + d) * E
            : word_tab + (size_t)ni * E;
        const float sgn = is_pos ? -1.0f : 1.0f;

        const float4 x1 = *reinterpret_cast<const float4*>(row + sl * 4);
        const float4 x2 = *reinterpret_cast<const float4*>(row + 64 + sl * 4);

        float v;
        v = x1.x * rv1.x;
        v = fmaf(x1.y, rv1.y, v);
        v = fmaf(x1.z, rv1.z, v);
        v = fmaf(x1.w, rv1.w, v);
        v = fmaf(x2.x, rv2.x, v);
        v = fmaf(x2.y, rv2.y, v);
        v = fmaf(x2.z, rv2.z, v);
        v = fmaf(x2.w, rv2.w, v);

        // 4-step butterfly within the 16-lane group
        v += __shfl_xor(v, 1);
        v += __shfl_xor(v, 2);
        v += __shfl_xor(v, 4);
        v += __shfl_xor(v, 8);

        const float term = m * stable_softplus(sgn * v);
        loss_acc += (sl == 0) ? term : 0.0f;
    }

    // ---- final wave reduction: loss sum + word count ----
    float cntv = (lane < W) ? md_l : 0.0f;   // md_l = mask[b*W+lane] for lane<W
    #pragma unroll
    for (int s = 32; s >= 1; s >>= 1) {
        loss_acc += __shfl_xor(loss_acc, s);
        cntv     += __shfl_xor(cntv, s);
    }

    if (lane == 0) {
        out_loss[b] = loss_acc / fmaxf(cntv, 1.0f);
    }
}

extern "C" void kernel_launch(void* const* d_in, const int* in_sizes, int n_in,
                              void* d_out, int out_size, void* d_ws, size_t ws_size,
                              hipStream_t stream)
{
    const int*   review_ids = (const int*)  d_in[0];
    const float* rw_emb     = (const float*)d_in[1];
    const float* mask       = (const float*)d_in[2];
    const int*   neg_idxs   = (const int*)  d_in[3];
    const float* word_tab   = (const float*)d_in[4];
    const float* rev_tab    = (const float*)d_in[5];

    const int B  = in_sizes[0];
    const int BW = in_sizes[2];          // B*W
    const int W  = BW / B;
    const int NN = in_sizes[3] / BW;     // n_negs

    float* out_rev  = (float*)d_out;
    float* out_loss = (float*)d_out + (size_t)B * 128;

    const int waves_per_blk = 4;                 // 256 threads
    const int grid = (B + waves_per_blk - 1) / waves_per_blk;
    pv_groupdot_kernel<<<grid, 256, 0, stream>>>(
        review_ids, rw_emb, mask, neg_idxs, word_tab, rev_tab,
        out_rev, out_loss, B, W, NN);
}